// Round 21
// baseline (328.659 us; speedup 1.0000x reference)
//
#include <hip/hip_runtime.h>
#include <stdint.h>

#define NROWS 262144
#define DDIM 128
#define NCLS 512
#define NHB 64  // hist/scatter blocks
constexpr float INV_BETA = 10.0f;
constexpr float EXP2_SCALE = 14.426950408889634f;  // 10 * log2(e)

typedef __bf16 v8bf __attribute__((ext_vector_type(8)));
typedef float v4f __attribute__((ext_vector_type(4)));

__device__ inline unsigned short f2bf(float f) {
    uint32_t u = __builtin_bit_cast(uint32_t, f);
    u += 0x7FFFu + ((u >> 16) & 1u);
    return (unsigned short)(u >> 16);
}
__device__ inline float bflo(uint32_t u) { return __builtin_bit_cast(float, u << 16); }
__device__ inline float bfhi(uint32_t u) { return __builtin_bit_cast(float, u & 0xFFFF0000u); }

#define GLL16(gsrc, ldst)                                                        \
    __builtin_amdgcn_global_load_lds(                                            \
        (const __attribute__((address_space(1))) void*)(uintptr_t)(gsrc),        \
        (__attribute__((address_space(3))) void*)(uintptr_t)(ldst), 16, 0, 0)

// K1 v5: streaming L2-normalize fp32 -> bf16 (blocks 0..8191); histogram fused.
__global__ __launch_bounds__(256) void k1_normalize(
    const float* __restrict__ in, const int* __restrict__ tgt,
    unsigned short* __restrict__ xb, int* __restrict__ bh) {
    __shared__ int h[NCLS];
    int t = threadIdx.x;
    if (blockIdx.x >= 8192) {
        int b = blockIdx.x - 8192;
        for (int i = t; i < NCLS; i += 256) h[i] = 0;
        __syncthreads();
        int base = b * (NROWS / NHB);
        for (int i = base + t; i < base + NROWS / NHB; i += 256)
            atomicAdd(&h[tgt[i]], 1);
        __syncthreads();
        for (int i = t; i < NCLS; i += 256)
            bh[b * NCLS + i] = h[i];
        return;
    }
    int w = t >> 6;
    int half = (t & 63) >> 5;
    int lane32 = t & 31;
    int hw = blockIdx.x * 8 + w * 2 + half;
    int r0 = hw * 4;
    float4 v[4];
#pragma unroll
    for (int j = 0; j < 4; ++j)
        v[j] = *reinterpret_cast<const float4*>(in + (size_t)(r0 + j) * DDIM + lane32 * 4);
    float s[4];
#pragma unroll
    for (int j = 0; j < 4; ++j)
        s[j] = v[j].x * v[j].x + v[j].y * v[j].y + v[j].z * v[j].z + v[j].w * v[j].w;
#pragma unroll
    for (int off = 1; off < 32; off <<= 1) {
#pragma unroll
        for (int j = 0; j < 4; ++j) s[j] += __shfl_xor(s[j], off);
    }
#pragma unroll
    for (int j = 0; j < 4; ++j) {
        float iv = rsqrtf(fmaxf(s[j], 1e-24f));
        ushort4 o;
        o.x = f2bf(v[j].x * iv); o.y = f2bf(v[j].y * iv);
        o.z = f2bf(v[j].z * iv); o.w = f2bf(v[j].w * iv);
        *reinterpret_cast<ushort4*>(xb + (size_t)(r0 + j) * DDIM + lane32 * 4) = o;
    }
}

// Prefix v3: bh column fully register-resident (64 independent loads pipeline;
// no serial load-latency chain). counts-sum, scan, and base-walk reuse arr.
__global__ __launch_bounds__(512) void k_prefix(
    const int* __restrict__ bh, int* __restrict__ counts, int* __restrict__ offs,
    int* __restrict__ base, float* __restrict__ nabsG, float* __restrict__ out) {
    __shared__ int sc[NCLS];
    __shared__ int za;
    int t = threadIdx.x;
    int arr[NHB];
#pragma unroll
    for (int b = 0; b < NHB; ++b) arr[b] = bh[b * NCLS + t];
    int cnt = 0;
#pragma unroll
    for (int b = 0; b < NHB; ++b) cnt += arr[b];
    counts[t] = cnt;
    sc[t] = cnt;
    if (t == 0) za = 0;
    __syncthreads();
    for (int off = 1; off < NCLS; off <<= 1) {
        int v = (t >= off) ? sc[t - off] : 0;
        __syncthreads();
        sc[t] += v;
        __syncthreads();
    }
    int excl = sc[t] - cnt;
    offs[t] = excl;
    if (cnt == 0) atomicAdd(&za, 1);
    int run = excl;
#pragma unroll
    for (int b = 0; b < NHB; ++b) {
        base[b * NCLS + t] = run;
        run += arr[b];
    }
    __syncthreads();
    if (t == 0) { *nabsG = (float)za; *out = 0.0f; }
}

__global__ __launch_bounds__(256) void k_scatter(
    const int* __restrict__ tgt, const int* __restrict__ base, int* __restrict__ ridx) {
    __shared__ int cur[NCLS];
    int t = threadIdx.x;
    int b = blockIdx.x;
    cur[t] = base[b * NCLS + t];
    cur[t + 256] = base[b * NCLS + t + 256];
    __syncthreads();
    int r0 = b * (NROWS / NHB);
    for (int i = t; i < NROWS / NHB; i += 256) {
        int row = r0 + i;
        int c = tgt[row];
        int pos = atomicAdd(&cur[c], 1);
        ridx[pos] = row;
    }
}

// centers gather body (MLP 16).
__device__ inline void centers_gather(
    const uint32_t* __restrict__ xb32, const int* __restrict__ ridx,
    int start, int lo, int hi, int l, float& a0, float& a1) {
    int i = lo;
    for (; i + 16 <= hi; i += 16) {
        int id[16]; uint32_t v[16];
#pragma unroll
        for (int j = 0; j < 16; ++j) id[j] = ridx[start + i + j];
#pragma unroll
        for (int j = 0; j < 16; ++j) v[j] = xb32[(size_t)id[j] * 64 + l];
#pragma unroll
        for (int j = 0; j < 16; ++j) { a0 += bflo(v[j]); a1 += bfhi(v[j]); }
    }
    for (; i < hi; ++i) {
        uint32_t v = xb32[(size_t)ridx[start + i] * 64 + l];
        a0 += bflo(v); a1 += bfhi(v);
    }
}

// Per-class mean + L2-normalize -> bf16 centers pre-scaled by 10*log2(e).
__global__ __launch_bounds__(512) void k_centers(
    const unsigned short* __restrict__ xb, const int* __restrict__ ridx,
    const int* __restrict__ counts, const int* __restrict__ offs,
    unsigned short* __restrict__ cen, float* __restrict__ out) {
    __shared__ float2 sP[8][64];
    int t = threadIdx.x, w = t >> 6, l = t & 63;
    int cl = blockIdx.x;
    int cnt = counts[cl], start = offs[cl];
    float a0 = 0.0f, a1 = 0.0f;
    int per = (cnt + 7) >> 3;
    int lo = w * per, hi = min(cnt, lo + per);
    centers_gather((const uint32_t*)xb, ridx, start, lo, hi, l, a0, a1);
    sP[w][l] = make_float2(a0, a1);
    __syncthreads();
    if (w == 0) {
        float c0 = 0.0f, c1 = 0.0f;
#pragma unroll
        for (int q = 0; q < 8; ++q) { c0 += sP[q][l].x; c1 += sP[q][l].y; }
        float fc = fmaxf((float)cnt, 1.0f);
        c0 /= fc; c1 /= fc;
        float ss = c0 * c0 + c1 * c1;
        for (int off = 1; off < 64; off <<= 1) ss += __shfl_xor(ss, off);
        float inv = EXP2_SCALE / fmaxf(sqrtf(ss), 1e-12f);
        ushort2 o;
        o.x = f2bf(c0 * inv); o.y = f2bf(c1 * inv);
        *reinterpret_cast<ushort2*>(cen + (size_t)cl * DDIM + l * 2) = o;
        if (l == 0)
            atomicAdd(out, -(float)cnt * sqrtf(ss) * (INV_BETA / (float)NROWS));
    }
}

// K4 v8 body. REPS>1 repeats ONLY the m-sweep (staging outside) -> probe
// isolates main-loop cost from prologue cost.
template <int REPS>
__device__ inline void k4_body(
    const unsigned short* __restrict__ xb, const unsigned short* __restrict__ cen,
    const float* __restrict__ nabsG, float* __restrict__ out) {
    extern __shared__ char lds[];
    char* cenL = lds;                       // 131072
    float* wsum = (float*)(lds + 131072);   // 16 f32
    int t = threadIdx.x, w = t >> 6, l = t & 63;
    int lm = l & 15, lk = l >> 4;
    float nabs = *nabsG;

    int s0 = blockIdx.x * 1024 + w * 64;
    const char* xB = (const char*)xb;
    v8bf bfr[4][4];
#pragma unroll
    for (int n = 0; n < 4; ++n)
#pragma unroll
        for (int kc = 0; kc < 4; ++kc)
            bfr[n][kc] = *reinterpret_cast<const v8bf*>(
                xB + (size_t)(s0 + n * 16 + lm) * 256 + kc * 64 + lk * 16);

    const char* cB = (const char*)cen;
#pragma unroll
    for (int i = 0; i < 8; ++i) {
        int chunk = w * 8 + i;            // 0..127
        int m = chunk >> 2, kc = chunk & 3;
        int src = (m * 16 + lm) * 256 + kc * 64 + lk * 16;
        GLL16(cB + src, cenL + chunk * 1024);
    }
    asm volatile("s_waitcnt vmcnt(0)" ::: "memory");
    __syncthreads();

    float lossAcc = 0.0f;
    for (int rep = 0; rep < REPS; ++rep) {
        asm volatile("" ::: "memory");
        float den[4] = {0.0f, 0.0f, 0.0f, 0.0f};
        for (int m = 0; m < 32; ++m) {
            v8bf a[4];
#pragma unroll
            for (int kc = 0; kc < 4; ++kc)
                a[kc] = *reinterpret_cast<const v8bf*>(cenL + m * 4096 + kc * 1024 + l * 16);
            v4f acc[4];
            v4f zero = {0.0f, 0.0f, 0.0f, 0.0f};
#pragma unroll
            for (int n = 0; n < 4; ++n) acc[n] = zero;
#pragma unroll
            for (int kc = 0; kc < 4; ++kc)
#pragma unroll
                for (int n = 0; n < 4; ++n)
                    acc[n] = __builtin_amdgcn_mfma_f32_16x16x32_bf16(a[kc], bfr[n][kc], acc[n], 0, 0, 0);
#pragma unroll
            for (int n = 0; n < 4; ++n)
#pragma unroll
                for (int rr = 0; rr < 4; ++rr)
                    den[n] += __builtin_amdgcn_exp2f(acc[n][rr]);
        }
#pragma unroll
        for (int n = 0; n < 4; ++n) {
            float d = den[n];
            d += __shfl_xor(d, 16);
            d += __shfl_xor(d, 32);
            if (l < 16) lossAcc += __logf(d - nabs);
        }
    }
#pragma unroll
    for (int off = 1; off < 64; off <<= 1) lossAcc += __shfl_xor(lossAcc, off);
    if (l == 0) wsum[w] = lossAcc;
    __syncthreads();
    if (t == 0) {
        float s = 0.0f;
#pragma unroll
        for (int q = 0; q < 16; ++q) s += wsum[q];
        atomicAdd(out, s * (1.0f / ((float)NROWS * REPS)));
    }
}

__global__ __launch_bounds__(1024) void k4_loss(
    const unsigned short* __restrict__ xb, const unsigned short* __restrict__ cen,
    const float* __restrict__ nabsG, float* __restrict__ out) {
    k4_body<1>(xb, cen, nabsG, out);
}

__global__ __launch_bounds__(1024) void k4_probe(
    const unsigned short* __restrict__ xb, const unsigned short* __restrict__ cen,
    const float* __restrict__ nabsG, float* __restrict__ out) {
    k4_body<8>(xb, cen, nabsG, out);
}

extern "C" void kernel_launch(void* const* d_in, const int* in_sizes, int n_in,
                              void* d_out, int out_size, void* d_ws, size_t ws_size,
                              hipStream_t stream) {
    const float* in = (const float*)d_in[0];
    const int* tgt = (const int*)d_in[1];
    float* out = (float*)d_out;
    char* ws = (char*)d_ws;
    unsigned short* xb = (unsigned short*)(ws);              // 67108864 B
    int* counts = (int*)(ws + 67108864);                     // 2048 B
    int* offs = (int*)(ws + 67110912);                       // 2048 B
    float* nabsG = (float*)(ws + 67112960);                  // 256 B (pad)
    unsigned short* cen = (unsigned short*)(ws + 67115264);  // 131072 B
    int* ridx = (int*)(ws + 67246336);                       // 1048576 B
    int* bh = (int*)(ws + 68294912);                         // 131072 B
    int* base = (int*)(ws + 68557056);                       // 131072 B
    float* out2 = (float*)(ws + 70254592);                   // probe scratch

    (void)hipFuncSetAttribute((const void*)k4_loss,
                              hipFuncAttributeMaxDynamicSharedMemorySize, 131136);
    (void)hipFuncSetAttribute((const void*)k4_probe,
                              hipFuncAttributeMaxDynamicSharedMemorySize, 131136);

    hipLaunchKernelGGL(k1_normalize, dim3(8192 + NHB), dim3(256), 0, stream, in, tgt, xb, bh);
    hipLaunchKernelGGL(k_prefix, dim3(1), dim3(512), 0, stream, bh, counts, offs, base, nabsG, out);
    hipLaunchKernelGGL(k_scatter, dim3(NHB), dim3(256), 0, stream, tgt, base, ridx);
    hipLaunchKernelGGL(k_centers, dim3(NCLS), dim3(512), 0, stream, xb, ridx, counts, offs, cen, out);
    hipLaunchKernelGGL(k4_loss, dim3(256), dim3(1024), 131136, stream, xb, cen, nabsG, out);

    // probe: x8 m-sweep reps, staging excluded -> main-loop cost = dur/8
    hipLaunchKernelGGL(k4_probe, dim3(256), dim3(1024), 131136, stream, xb, cen, nabsG, out2);
}

// Round 22
// 133.163 us; speedup vs baseline: 2.4681x; 2.4681x over previous
//
#include <hip/hip_runtime.h>
#include <stdint.h>

#define NROWS 262144
#define DDIM 128
#define NCLS 512
#define NHB 64  // hist/scatter blocks
constexpr float INV_BETA = 10.0f;
constexpr float EXP2_SCALE = 14.426950408889634f;  // 10 * log2(e)

typedef __bf16 v8bf __attribute__((ext_vector_type(8)));
typedef float v4f __attribute__((ext_vector_type(4)));

__device__ inline unsigned short f2bf(float f) {
    uint32_t u = __builtin_bit_cast(uint32_t, f);
    u += 0x7FFFu + ((u >> 16) & 1u);
    return (unsigned short)(u >> 16);
}
__device__ inline float bflo(uint32_t u) { return __builtin_bit_cast(float, u << 16); }
__device__ inline float bfhi(uint32_t u) { return __builtin_bit_cast(float, u & 0xFFFF0000u); }

#define GLL16(gsrc, ldst)                                                        \
    __builtin_amdgcn_global_load_lds(                                            \
        (const __attribute__((address_space(1))) void*)(uintptr_t)(gsrc),        \
        (__attribute__((address_space(3))) void*)(uintptr_t)(ldst), 16, 0, 0)

// K1 v5: streaming L2-normalize fp32 -> bf16 (blocks 0..8191); histogram fused.
__global__ __launch_bounds__(256) void k1_normalize(
    const float* __restrict__ in, const int* __restrict__ tgt,
    unsigned short* __restrict__ xb, int* __restrict__ bh) {
    __shared__ int h[NCLS];
    int t = threadIdx.x;
    if (blockIdx.x >= 8192) {
        int b = blockIdx.x - 8192;
        for (int i = t; i < NCLS; i += 256) h[i] = 0;
        __syncthreads();
        int base = b * (NROWS / NHB);
        for (int i = base + t; i < base + NROWS / NHB; i += 256)
            atomicAdd(&h[tgt[i]], 1);
        __syncthreads();
        for (int i = t; i < NCLS; i += 256)
            bh[b * NCLS + i] = h[i];
        return;
    }
    int w = t >> 6;
    int half = (t & 63) >> 5;
    int lane32 = t & 31;
    int hw = blockIdx.x * 8 + w * 2 + half;
    int r0 = hw * 4;
    float4 v[4];
#pragma unroll
    for (int j = 0; j < 4; ++j)
        v[j] = *reinterpret_cast<const float4*>(in + (size_t)(r0 + j) * DDIM + lane32 * 4);
    float s[4];
#pragma unroll
    for (int j = 0; j < 4; ++j)
        s[j] = v[j].x * v[j].x + v[j].y * v[j].y + v[j].z * v[j].z + v[j].w * v[j].w;
#pragma unroll
    for (int off = 1; off < 32; off <<= 1) {
#pragma unroll
        for (int j = 0; j < 4; ++j) s[j] += __shfl_xor(s[j], off);
    }
#pragma unroll
    for (int j = 0; j < 4; ++j) {
        float iv = rsqrtf(fmaxf(s[j], 1e-24f));
        ushort4 o;
        o.x = f2bf(v[j].x * iv); o.y = f2bf(v[j].y * iv);
        o.z = f2bf(v[j].z * iv); o.w = f2bf(v[j].w * iv);
        *reinterpret_cast<ushort4*>(xb + (size_t)(r0 + j) * DDIM + lane32 * 4) = o;
    }
}

// Prefix v3: bh column register-resident; no serial load-latency chain.
__global__ __launch_bounds__(512) void k_prefix(
    const int* __restrict__ bh, int* __restrict__ counts, int* __restrict__ offs,
    int* __restrict__ base, float* __restrict__ nabsG, float* __restrict__ out) {
    __shared__ int sc[NCLS];
    __shared__ int za;
    int t = threadIdx.x;
    int arr[NHB];
#pragma unroll
    for (int b = 0; b < NHB; ++b) arr[b] = bh[b * NCLS + t];
    int cnt = 0;
#pragma unroll
    for (int b = 0; b < NHB; ++b) cnt += arr[b];
    counts[t] = cnt;
    sc[t] = cnt;
    if (t == 0) za = 0;
    __syncthreads();
    for (int off = 1; off < NCLS; off <<= 1) {
        int v = (t >= off) ? sc[t - off] : 0;
        __syncthreads();
        sc[t] += v;
        __syncthreads();
    }
    int excl = sc[t] - cnt;
    offs[t] = excl;
    if (cnt == 0) atomicAdd(&za, 1);
    int run = excl;
#pragma unroll
    for (int b = 0; b < NHB; ++b) {
        base[b * NCLS + t] = run;
        run += arr[b];
    }
    __syncthreads();
    if (t == 0) { *nabsG = (float)za; *out = 0.0f; }
}

__global__ __launch_bounds__(256) void k_scatter(
    const int* __restrict__ tgt, const int* __restrict__ base, int* __restrict__ ridx) {
    __shared__ int cur[NCLS];
    int t = threadIdx.x;
    int b = blockIdx.x;
    cur[t] = base[b * NCLS + t];
    cur[t + 256] = base[b * NCLS + t + 256];
    __syncthreads();
    int r0 = b * (NROWS / NHB);
    for (int i = t; i < NROWS / NHB; i += 256) {
        int row = r0 + i;
        int c = tgt[row];
        int pos = atomicAdd(&cur[c], 1);
        ridx[pos] = row;
    }
}

// centers gather body (MLP 16).
__device__ inline void centers_gather(
    const uint32_t* __restrict__ xb32, const int* __restrict__ ridx,
    int start, int lo, int hi, int l, float& a0, float& a1) {
    int i = lo;
    for (; i + 16 <= hi; i += 16) {
        int id[16]; uint32_t v[16];
#pragma unroll
        for (int j = 0; j < 16; ++j) id[j] = ridx[start + i + j];
#pragma unroll
        for (int j = 0; j < 16; ++j) v[j] = xb32[(size_t)id[j] * 64 + l];
#pragma unroll
        for (int j = 0; j < 16; ++j) { a0 += bflo(v[j]); a1 += bfhi(v[j]); }
    }
    for (; i < hi; ++i) {
        uint32_t v = xb32[(size_t)ridx[start + i] * 64 + l];
        a0 += bflo(v); a1 += bfhi(v);
    }
}

// Per-class mean + L2-normalize -> bf16 centers pre-scaled by 10*log2(e).
__global__ __launch_bounds__(512) void k_centers(
    const unsigned short* __restrict__ xb, const int* __restrict__ ridx,
    const int* __restrict__ counts, const int* __restrict__ offs,
    unsigned short* __restrict__ cen, float* __restrict__ out) {
    __shared__ float2 sP[8][64];
    int t = threadIdx.x, w = t >> 6, l = t & 63;
    int cl = blockIdx.x;
    int cnt = counts[cl], start = offs[cl];
    float a0 = 0.0f, a1 = 0.0f;
    int per = (cnt + 7) >> 3;
    int lo = w * per, hi = min(cnt, lo + per);
    centers_gather((const uint32_t*)xb, ridx, start, lo, hi, l, a0, a1);
    sP[w][l] = make_float2(a0, a1);
    __syncthreads();
    if (w == 0) {
        float c0 = 0.0f, c1 = 0.0f;
#pragma unroll
        for (int q = 0; q < 8; ++q) { c0 += sP[q][l].x; c1 += sP[q][l].y; }
        float fc = fmaxf((float)cnt, 1.0f);
        c0 /= fc; c1 /= fc;
        float ss = c0 * c0 + c1 * c1;
        for (int off = 1; off < 64; off <<= 1) ss += __shfl_xor(ss, off);
        float inv = EXP2_SCALE / fmaxf(sqrtf(ss), 1e-12f);
        ushort2 o;
        o.x = f2bf(c0 * inv); o.y = f2bf(c1 * inv);
        *reinterpret_cast<ushort2*>(cen + (size_t)cl * DDIM + l * 2) = o;
        if (l == 0)
            atomicAdd(out, -(float)cnt * sqrtf(ss) * (INV_BETA / (float)NROWS));
    }
}

// K4 v9: fragment-ordered LDS + PING-PONG accumulators. The WAR hazard
// (single acc reused per m-iter forced exp2 to drain before next MFMAs)
// capped MfmaUtil at 52% (m-probe, R21). accA/accB + aA/aB let MFMAs for
// m+1 issue while exp2 drains m on the VALU pipe.
#define LOAD_A(dst, m)                                                          \
    _Pragma("unroll")                                                           \
    for (int kc = 0; kc < 4; ++kc)                                              \
        dst[kc] = *reinterpret_cast<const v8bf*>(cenL + (m) * 4096 + kc * 1024 + l * 16);
#define MFMA_ACC(acc, a)                                                        \
    _Pragma("unroll")                                                           \
    for (int n = 0; n < 4; ++n) acc[n] = zero;                                  \
    _Pragma("unroll")                                                           \
    for (int kc = 0; kc < 4; ++kc)                                              \
        _Pragma("unroll")                                                       \
        for (int n = 0; n < 4; ++n)                                             \
            acc[n] = __builtin_amdgcn_mfma_f32_16x16x32_bf16(a[kc], bfr[n][kc], acc[n], 0, 0, 0);
#define EXP2_ACC(acc)                                                           \
    _Pragma("unroll")                                                           \
    for (int n = 0; n < 4; ++n)                                                 \
        _Pragma("unroll")                                                       \
        for (int rr = 0; rr < 4; ++rr) den[n] += __builtin_amdgcn_exp2f(acc[n][rr]);

__global__ __launch_bounds__(1024) void k4_loss(
    const unsigned short* __restrict__ xb, const unsigned short* __restrict__ cen,
    const float* __restrict__ nabsG, float* __restrict__ out) {
    extern __shared__ char lds[];
    char* cenL = lds;                       // 131072
    float* wsum = (float*)(lds + 131072);   // 16 f32
    int t = threadIdx.x, w = t >> 6, l = t & 63;
    int lm = l & 15, lk = l >> 4;
    float nabs = *nabsG;

    int s0 = blockIdx.x * 1024 + w * 64;
    const char* xB = (const char*)xb;
    v8bf bfr[4][4];
#pragma unroll
    for (int n = 0; n < 4; ++n)
#pragma unroll
        for (int kc = 0; kc < 4; ++kc)
            bfr[n][kc] = *reinterpret_cast<const v8bf*>(
                xB + (size_t)(s0 + n * 16 + lm) * 256 + kc * 64 + lk * 16);

    const char* cB = (const char*)cen;
#pragma unroll
    for (int i = 0; i < 8; ++i) {
        int chunk = w * 8 + i;            // 0..127
        int m = chunk >> 2, kc = chunk & 3;
        int src = (m * 16 + lm) * 256 + kc * 64 + lk * 16;
        GLL16(cB + src, cenL + chunk * 1024);
    }
    asm volatile("s_waitcnt vmcnt(0)" ::: "memory");
    __syncthreads();

    float den[4] = {0.0f, 0.0f, 0.0f, 0.0f};
    v4f zero = {0.0f, 0.0f, 0.0f, 0.0f};
    v8bf aA[4], aB[4];
    v4f accA[4], accB[4];

    LOAD_A(aA, 0)
    MFMA_ACC(accA, aA)               // m = 0
#pragma unroll 1
    for (int i = 0; i < 15; ++i) {
        LOAD_A(aB, 2 * i + 1)
        MFMA_ACC(accB, aB)           // m = 2i+1 issues while...
        EXP2_ACC(accA)               // ...exp2 drains m = 2i
        LOAD_A(aA, 2 * i + 2)
        MFMA_ACC(accA, aA)           // m = 2i+2
        EXP2_ACC(accB)               // drains m = 2i+1
    }
    LOAD_A(aB, 31)
    MFMA_ACC(accB, aB)               // m = 31
    EXP2_ACC(accA)                   // m = 30
    EXP2_ACC(accB)                   // m = 31

    float lossAcc = 0.0f;
#pragma unroll
    for (int n = 0; n < 4; ++n) {
        float d = den[n];
        d += __shfl_xor(d, 16);
        d += __shfl_xor(d, 32);
        if (l < 16) lossAcc += __logf(d - nabs);
    }
#pragma unroll
    for (int off = 1; off < 64; off <<= 1) lossAcc += __shfl_xor(lossAcc, off);
    if (l == 0) wsum[w] = lossAcc;
    __syncthreads();
    if (t == 0) {
        float s = 0.0f;
#pragma unroll
        for (int q = 0; q < 16; ++q) s += wsum[q];
        atomicAdd(out, s * (1.0f / NROWS));
    }
}

extern "C" void kernel_launch(void* const* d_in, const int* in_sizes, int n_in,
                              void* d_out, int out_size, void* d_ws, size_t ws_size,
                              hipStream_t stream) {
    const float* in = (const float*)d_in[0];
    const int* tgt = (const int*)d_in[1];
    float* out = (float*)d_out;
    char* ws = (char*)d_ws;
    unsigned short* xb = (unsigned short*)(ws);              // 67108864 B
    int* counts = (int*)(ws + 67108864);                     // 2048 B
    int* offs = (int*)(ws + 67110912);                       // 2048 B
    float* nabsG = (float*)(ws + 67112960);                  // 256 B (pad)
    unsigned short* cen = (unsigned short*)(ws + 67115264);  // 131072 B
    int* ridx = (int*)(ws + 67246336);                       // 1048576 B
    int* bh = (int*)(ws + 68294912);                         // 131072 B
    int* base = (int*)(ws + 68557056);                       // 131072 B

    (void)hipFuncSetAttribute((const void*)k4_loss,
                              hipFuncAttributeMaxDynamicSharedMemorySize, 131136);

    hipLaunchKernelGGL(k1_normalize, dim3(8192 + NHB), dim3(256), 0, stream, in, tgt, xb, bh);
    hipLaunchKernelGGL(k_prefix, dim3(1), dim3(512), 0, stream, bh, counts, offs, base, nabsG, out);
    hipLaunchKernelGGL(k_scatter, dim3(NHB), dim3(256), 0, stream, tgt, base, ridx);
    hipLaunchKernelGGL(k_centers, dim3(NCLS), dim3(512), 0, stream, xb, ridx, counts, offs, cen, out);
    hipLaunchKernelGGL(k4_loss, dim3(256), dim3(1024), 131136, stream, xb, cen, nabsG, out);
}

// Round 23
// 131.167 us; speedup vs baseline: 2.5056x; 1.0152x over previous
//
#include <hip/hip_runtime.h>
#include <stdint.h>

#define NROWS 262144
#define DDIM 128
#define NCLS 512
#define NHB 64  // hist/scatter blocks
constexpr float INV_BETA = 10.0f;
constexpr float EXP2_SCALE = 14.426950408889634f;  // 10 * log2(e)

typedef __bf16 v8bf __attribute__((ext_vector_type(8)));
typedef float v4f __attribute__((ext_vector_type(4)));

__device__ inline unsigned short f2bf(float f) {
    uint32_t u = __builtin_bit_cast(uint32_t, f);
    u += 0x7FFFu + ((u >> 16) & 1u);
    return (unsigned short)(u >> 16);
}
__device__ inline float bflo(uint32_t u) { return __builtin_bit_cast(float, u << 16); }
__device__ inline float bfhi(uint32_t u) { return __builtin_bit_cast(float, u & 0xFFFF0000u); }

#define GLL16(gsrc, ldst)                                                        \
    __builtin_amdgcn_global_load_lds(                                            \
        (const __attribute__((address_space(1))) void*)(uintptr_t)(gsrc),        \
        (__attribute__((address_space(3))) void*)(uintptr_t)(ldst), 16, 0, 0)

// K1 v5: streaming L2-normalize fp32 -> bf16 (blocks 0..8191); histogram fused.
__global__ __launch_bounds__(256) void k1_normalize(
    const float* __restrict__ in, const int* __restrict__ tgt,
    unsigned short* __restrict__ xb, int* __restrict__ bh) {
    __shared__ int h[NCLS];
    int t = threadIdx.x;
    if (blockIdx.x >= 8192) {
        int b = blockIdx.x - 8192;
        for (int i = t; i < NCLS; i += 256) h[i] = 0;
        __syncthreads();
        int base = b * (NROWS / NHB);
        for (int i = base + t; i < base + NROWS / NHB; i += 256)
            atomicAdd(&h[tgt[i]], 1);
        __syncthreads();
        for (int i = t; i < NCLS; i += 256)
            bh[b * NCLS + i] = h[i];
        return;
    }
    int w = t >> 6;
    int half = (t & 63) >> 5;
    int lane32 = t & 31;
    int hw = blockIdx.x * 8 + w * 2 + half;
    int r0 = hw * 4;
    float4 v[4];
#pragma unroll
    for (int j = 0; j < 4; ++j)
        v[j] = *reinterpret_cast<const float4*>(in + (size_t)(r0 + j) * DDIM + lane32 * 4);
    float s[4];
#pragma unroll
    for (int j = 0; j < 4; ++j)
        s[j] = v[j].x * v[j].x + v[j].y * v[j].y + v[j].z * v[j].z + v[j].w * v[j].w;
#pragma unroll
    for (int off = 1; off < 32; off <<= 1) {
#pragma unroll
        for (int j = 0; j < 4; ++j) s[j] += __shfl_xor(s[j], off);
    }
#pragma unroll
    for (int j = 0; j < 4; ++j) {
        float iv = rsqrtf(fmaxf(s[j], 1e-24f));
        ushort4 o;
        o.x = f2bf(v[j].x * iv); o.y = f2bf(v[j].y * iv);
        o.z = f2bf(v[j].z * iv); o.w = f2bf(v[j].w * iv);
        *reinterpret_cast<ushort4*>(xb + (size_t)(r0 + j) * DDIM + lane32 * 4) = o;
    }
}

// Prefix v3: bh column register-resident; no serial load-latency chain.
__global__ __launch_bounds__(512) void k_prefix(
    const int* __restrict__ bh, int* __restrict__ counts, int* __restrict__ offs,
    int* __restrict__ base, float* __restrict__ nabsG, float* __restrict__ out) {
    __shared__ int sc[NCLS];
    __shared__ int za;
    int t = threadIdx.x;
    int arr[NHB];
#pragma unroll
    for (int b = 0; b < NHB; ++b) arr[b] = bh[b * NCLS + t];
    int cnt = 0;
#pragma unroll
    for (int b = 0; b < NHB; ++b) cnt += arr[b];
    counts[t] = cnt;
    sc[t] = cnt;
    if (t == 0) za = 0;
    __syncthreads();
    for (int off = 1; off < NCLS; off <<= 1) {
        int v = (t >= off) ? sc[t - off] : 0;
        __syncthreads();
        sc[t] += v;
        __syncthreads();
    }
    int excl = sc[t] - cnt;
    offs[t] = excl;
    if (cnt == 0) atomicAdd(&za, 1);
    int run = excl;
#pragma unroll
    for (int b = 0; b < NHB; ++b) {
        base[b * NCLS + t] = run;
        run += arr[b];
    }
    __syncthreads();
    if (t == 0) { *nabsG = (float)za; *out = 0.0f; }
}

__global__ __launch_bounds__(256) void k_scatter(
    const int* __restrict__ tgt, const int* __restrict__ base, int* __restrict__ ridx) {
    __shared__ int cur[NCLS];
    int t = threadIdx.x;
    int b = blockIdx.x;
    cur[t] = base[b * NCLS + t];
    cur[t + 256] = base[b * NCLS + t + 256];
    __syncthreads();
    int r0 = b * (NROWS / NHB);
    for (int i = t; i < NROWS / NHB; i += 256) {
        int row = r0 + i;
        int c = tgt[row];
        int pos = atomicAdd(&cur[c], 1);
        ridx[pos] = row;
    }
}

// centers gather body (MLP 16).
__device__ inline void centers_gather(
    const uint32_t* __restrict__ xb32, const int* __restrict__ ridx,
    int start, int lo, int hi, int l, float& a0, float& a1) {
    int i = lo;
    for (; i + 16 <= hi; i += 16) {
        int id[16]; uint32_t v[16];
#pragma unroll
        for (int j = 0; j < 16; ++j) id[j] = ridx[start + i + j];
#pragma unroll
        for (int j = 0; j < 16; ++j) v[j] = xb32[(size_t)id[j] * 64 + l];
#pragma unroll
        for (int j = 0; j < 16; ++j) { a0 += bflo(v[j]); a1 += bfhi(v[j]); }
    }
    for (; i < hi; ++i) {
        uint32_t v = xb32[(size_t)ridx[start + i] * 64 + l];
        a0 += bflo(v); a1 += bfhi(v);
    }
}

// Per-class mean + L2-normalize -> bf16 centers pre-scaled by 10*log2(e).
__global__ __launch_bounds__(512) void k_centers(
    const unsigned short* __restrict__ xb, const int* __restrict__ ridx,
    const int* __restrict__ counts, const int* __restrict__ offs,
    unsigned short* __restrict__ cen, float* __restrict__ out) {
    __shared__ float2 sP[8][64];
    int t = threadIdx.x, w = t >> 6, l = t & 63;
    int cl = blockIdx.x;
    int cnt = counts[cl], start = offs[cl];
    float a0 = 0.0f, a1 = 0.0f;
    int per = (cnt + 7) >> 3;
    int lo = w * per, hi = min(cnt, lo + per);
    centers_gather((const uint32_t*)xb, ridx, start, lo, hi, l, a0, a1);
    sP[w][l] = make_float2(a0, a1);
    __syncthreads();
    if (w == 0) {
        float c0 = 0.0f, c1 = 0.0f;
#pragma unroll
        for (int q = 0; q < 8; ++q) { c0 += sP[q][l].x; c1 += sP[q][l].y; }
        float fc = fmaxf((float)cnt, 1.0f);
        c0 /= fc; c1 /= fc;
        float ss = c0 * c0 + c1 * c1;
        for (int off = 1; off < 64; off <<= 1) ss += __shfl_xor(ss, off);
        float inv = EXP2_SCALE / fmaxf(sqrtf(ss), 1e-12f);
        ushort2 o;
        o.x = f2bf(c0 * inv); o.y = f2bf(c1 * inv);
        *reinterpret_cast<ushort2*>(cen + (size_t)cl * DDIM + l * 2) = o;
        if (l == 0)
            atomicAdd(out, -(float)cnt * sqrtf(ss) * (INV_BETA / (float)NROWS));
    }
}

// K4 v9b: fragment-ordered LDS + MINIMAL ping-pong: double ONLY the
// accumulator (accA/accB, +16 VGPR over v8's 60), single shared a-buffer.
// exp2(accA) is independent of MFMA(accB) -> MFMA and VALU pipes overlap
// without the v9 register blow-up (v9: ~150 VGPR demand > 128 cap at
// 1024-thread blocks -> scratch spill, occupancy 1.5%, 2x regression).
#define LOAD_A(dst, m)                                                          \
    _Pragma("unroll")                                                           \
    for (int kc = 0; kc < 4; ++kc)                                              \
        dst[kc] = *reinterpret_cast<const v8bf*>(cenL + (m) * 4096 + kc * 1024 + l * 16);
#define MFMA_ACC(acc, a)                                                        \
    _Pragma("unroll")                                                           \
    for (int n = 0; n < 4; ++n) acc[n] = zero;                                  \
    _Pragma("unroll")                                                           \
    for (int kc = 0; kc < 4; ++kc)                                              \
        _Pragma("unroll")                                                       \
        for (int n = 0; n < 4; ++n)                                             \
            acc[n] = __builtin_amdgcn_mfma_f32_16x16x32_bf16(a[kc], bfr[n][kc], acc[n], 0, 0, 0);
#define EXP2_ACC(acc)                                                           \
    _Pragma("unroll")                                                           \
    for (int n = 0; n < 4; ++n)                                                 \
        _Pragma("unroll")                                                       \
        for (int rr = 0; rr < 4; ++rr) den[n] += __builtin_amdgcn_exp2f(acc[n][rr]);

__global__ __launch_bounds__(1024) void k4_loss(
    const unsigned short* __restrict__ xb, const unsigned short* __restrict__ cen,
    const float* __restrict__ nabsG, float* __restrict__ out) {
    extern __shared__ char lds[];
    char* cenL = lds;                       // 131072
    float* wsum = (float*)(lds + 131072);   // 16 f32
    int t = threadIdx.x, w = t >> 6, l = t & 63;
    int lm = l & 15, lk = l >> 4;
    float nabs = *nabsG;

    int s0 = blockIdx.x * 1024 + w * 64;
    const char* xB = (const char*)xb;
    v8bf bfr[4][4];
#pragma unroll
    for (int n = 0; n < 4; ++n)
#pragma unroll
        for (int kc = 0; kc < 4; ++kc)
            bfr[n][kc] = *reinterpret_cast<const v8bf*>(
                xB + (size_t)(s0 + n * 16 + lm) * 256 + kc * 64 + lk * 16);

    const char* cB = (const char*)cen;
#pragma unroll
    for (int i = 0; i < 8; ++i) {
        int chunk = w * 8 + i;            // 0..127
        int m = chunk >> 2, kc = chunk & 3;
        int src = (m * 16 + lm) * 256 + kc * 64 + lk * 16;
        GLL16(cB + src, cenL + chunk * 1024);
    }
    asm volatile("s_waitcnt vmcnt(0)" ::: "memory");
    __syncthreads();

    float den[4] = {0.0f, 0.0f, 0.0f, 0.0f};
    v4f zero = {0.0f, 0.0f, 0.0f, 0.0f};
    v8bf a[4];
    v4f accA[4], accB[4];

    LOAD_A(a, 0)
    MFMA_ACC(accA, a)                // m = 0
    for (int i = 0; i < 15; ++i) {
        LOAD_A(a, 2 * i + 1)
        MFMA_ACC(accB, a)            // m = 2i+1 issues while...
        EXP2_ACC(accA)               // ...exp2 drains m = 2i
        LOAD_A(a, 2 * i + 2)
        MFMA_ACC(accA, a)            // m = 2i+2
        EXP2_ACC(accB)               // drains m = 2i+1
    }
    LOAD_A(a, 31)
    MFMA_ACC(accB, a)                // m = 31
    EXP2_ACC(accA)                   // m = 30
    EXP2_ACC(accB)                   // m = 31

    float lossAcc = 0.0f;
#pragma unroll
    for (int n = 0; n < 4; ++n) {
        float d = den[n];
        d += __shfl_xor(d, 16);
        d += __shfl_xor(d, 32);
        if (l < 16) lossAcc += __logf(d - nabs);
    }
#pragma unroll
    for (int off = 1; off < 64; off <<= 1) lossAcc += __shfl_xor(lossAcc, off);
    if (l == 0) wsum[w] = lossAcc;
    __syncthreads();
    if (t == 0) {
        float s = 0.0f;
#pragma unroll
        for (int q = 0; q < 16; ++q) s += wsum[q];
        atomicAdd(out, s * (1.0f / NROWS));
    }
}

extern "C" void kernel_launch(void* const* d_in, const int* in_sizes, int n_in,
                              void* d_out, int out_size, void* d_ws, size_t ws_size,
                              hipStream_t stream) {
    const float* in = (const float*)d_in[0];
    const int* tgt = (const int*)d_in[1];
    float* out = (float*)d_out;
    char* ws = (char*)d_ws;
    unsigned short* xb = (unsigned short*)(ws);              // 67108864 B
    int* counts = (int*)(ws + 67108864);                     // 2048 B
    int* offs = (int*)(ws + 67110912);                       // 2048 B
    float* nabsG = (float*)(ws + 67112960);                  // 256 B (pad)
    unsigned short* cen = (unsigned short*)(ws + 67115264);  // 131072 B
    int* ridx = (int*)(ws + 67246336);                       // 1048576 B
    int* bh = (int*)(ws + 68294912);                         // 131072 B
    int* base = (int*)(ws + 68557056);                       // 131072 B

    (void)hipFuncSetAttribute((const void*)k4_loss,
                              hipFuncAttributeMaxDynamicSharedMemorySize, 131136);

    hipLaunchKernelGGL(k1_normalize, dim3(8192 + NHB), dim3(256), 0, stream, in, tgt, xb, bh);
    hipLaunchKernelGGL(k_prefix, dim3(1), dim3(512), 0, stream, bh, counts, offs, base, nabsG, out);
    hipLaunchKernelGGL(k_scatter, dim3(NHB), dim3(256), 0, stream, tgt, base, ridx);
    hipLaunchKernelGGL(k_centers, dim3(NCLS), dim3(512), 0, stream, xb, ridx, counts, offs, cen, out);
    hipLaunchKernelGGL(k4_loss, dim3(256), dim3(1024), 131136, stream, xb, cen, nabsG, out);
}

// Round 24
// 116.134 us; speedup vs baseline: 2.8300x; 1.1294x over previous
//
#include <hip/hip_runtime.h>
#include <stdint.h>

#define NROWS 262144
#define DDIM 128
#define NCLS 512
#define NHB 64  // hist/scatter blocks
constexpr float INV_BETA = 10.0f;
constexpr float EXP2_SCALE = 14.426950408889634f;  // 10 * log2(e)

typedef __bf16 v8bf __attribute__((ext_vector_type(8)));
typedef float v4f __attribute__((ext_vector_type(4)));

__device__ inline unsigned short f2bf(float f) {
    uint32_t u = __builtin_bit_cast(uint32_t, f);
    u += 0x7FFFu + ((u >> 16) & 1u);
    return (unsigned short)(u >> 16);
}
__device__ inline float bflo(uint32_t u) { return __builtin_bit_cast(float, u << 16); }
__device__ inline float bfhi(uint32_t u) { return __builtin_bit_cast(float, u & 0xFFFF0000u); }

#define GLL16(gsrc, ldst)                                                        \
    __builtin_amdgcn_global_load_lds(                                            \
        (const __attribute__((address_space(1))) void*)(uintptr_t)(gsrc),        \
        (__attribute__((address_space(3))) void*)(uintptr_t)(ldst), 16, 0, 0)

// K1 v5: streaming L2-normalize fp32 -> bf16 (blocks 0..8191); histogram fused.
__global__ __launch_bounds__(256) void k1_normalize(
    const float* __restrict__ in, const int* __restrict__ tgt,
    unsigned short* __restrict__ xb, int* __restrict__ bh) {
    __shared__ int h[NCLS];
    int t = threadIdx.x;
    if (blockIdx.x >= 8192) {
        int b = blockIdx.x - 8192;
        for (int i = t; i < NCLS; i += 256) h[i] = 0;
        __syncthreads();
        int base = b * (NROWS / NHB);
        for (int i = base + t; i < base + NROWS / NHB; i += 256)
            atomicAdd(&h[tgt[i]], 1);
        __syncthreads();
        for (int i = t; i < NCLS; i += 256)
            bh[b * NCLS + i] = h[i];
        return;
    }
    int w = t >> 6;
    int half = (t & 63) >> 5;
    int lane32 = t & 31;
    int hw = blockIdx.x * 8 + w * 2 + half;
    int r0 = hw * 4;
    float4 v[4];
#pragma unroll
    for (int j = 0; j < 4; ++j)
        v[j] = *reinterpret_cast<const float4*>(in + (size_t)(r0 + j) * DDIM + lane32 * 4);
    float s[4];
#pragma unroll
    for (int j = 0; j < 4; ++j)
        s[j] = v[j].x * v[j].x + v[j].y * v[j].y + v[j].z * v[j].z + v[j].w * v[j].w;
#pragma unroll
    for (int off = 1; off < 32; off <<= 1) {
#pragma unroll
        for (int j = 0; j < 4; ++j) s[j] += __shfl_xor(s[j], off);
    }
#pragma unroll
    for (int j = 0; j < 4; ++j) {
        float iv = rsqrtf(fmaxf(s[j], 1e-24f));
        ushort4 o;
        o.x = f2bf(v[j].x * iv); o.y = f2bf(v[j].y * iv);
        o.z = f2bf(v[j].z * iv); o.w = f2bf(v[j].w * iv);
        *reinterpret_cast<ushort4*>(xb + (size_t)(r0 + j) * DDIM + lane32 * 4) = o;
    }
}

// Scatter v3 (prefix FUSED): each of 64 blocks recomputes the class scan from
// its register-resident bh column (cheap, deterministic, identical across
// blocks); myBase = excl + sum_{bb<b} arr[bb]. Block 0 also writes counts/
// offs/nabs and zeroes out. Kills the separate 1-block prefix launch + gap.
__global__ __launch_bounds__(512) void k_scatter(
    const int* __restrict__ bh, const int* __restrict__ tgt,
    int* __restrict__ counts, int* __restrict__ offs, int* __restrict__ ridx,
    float* __restrict__ nabsG, float* __restrict__ out) {
    __shared__ int sc[NCLS];
    __shared__ int cur[NCLS];
    __shared__ int za;
    int t = threadIdx.x;  // == class id
    int b = blockIdx.x;
    int arr[NHB];
#pragma unroll
    for (int bb = 0; bb < NHB; ++bb) arr[bb] = bh[bb * NCLS + t];
    int cnt = 0;
#pragma unroll
    for (int bb = 0; bb < NHB; ++bb) cnt += arr[bb];
    sc[t] = cnt;
    if (t == 0) za = 0;
    __syncthreads();
    for (int off = 1; off < NCLS; off <<= 1) {
        int v = (t >= off) ? sc[t - off] : 0;
        __syncthreads();
        sc[t] += v;
        __syncthreads();
    }
    int excl = sc[t] - cnt;
    int myBase = excl;
    for (int bb = 0; bb < b; ++bb) myBase += arr[bb];
    cur[t] = myBase;
    if (b == 0) {
        counts[t] = cnt;
        offs[t] = excl;
        if (cnt == 0) atomicAdd(&za, 1);
    }
    __syncthreads();
    if (b == 0 && t == 0) { *nabsG = (float)za; *out = 0.0f; }
    int r0 = b * (NROWS / NHB);
    for (int i = t; i < NROWS / NHB; i += 512) {
        int row = r0 + i;
        int c = tgt[row];
        int pos = atomicAdd(&cur[c], 1);
        ridx[pos] = row;
    }
}

// centers gather body (MLP 16).
__device__ inline void centers_gather(
    const uint32_t* __restrict__ xb32, const int* __restrict__ ridx,
    int start, int lo, int hi, int l, float& a0, float& a1) {
    int i = lo;
    for (; i + 16 <= hi; i += 16) {
        int id[16]; uint32_t v[16];
#pragma unroll
        for (int j = 0; j < 16; ++j) id[j] = ridx[start + i + j];
#pragma unroll
        for (int j = 0; j < 16; ++j) v[j] = xb32[(size_t)id[j] * 64 + l];
#pragma unroll
        for (int j = 0; j < 16; ++j) { a0 += bflo(v[j]); a1 += bfhi(v[j]); }
    }
    for (; i < hi; ++i) {
        uint32_t v = xb32[(size_t)ridx[start + i] * 64 + l];
        a0 += bflo(v); a1 += bfhi(v);
    }
}

// Per-class mean + L2-normalize -> bf16 centers pre-scaled by 10*log2(e).
__global__ __launch_bounds__(512) void k_centers(
    const unsigned short* __restrict__ xb, const int* __restrict__ ridx,
    const int* __restrict__ counts, const int* __restrict__ offs,
    unsigned short* __restrict__ cen, float* __restrict__ out) {
    __shared__ float2 sP[8][64];
    int t = threadIdx.x, w = t >> 6, l = t & 63;
    int cl = blockIdx.x;
    int cnt = counts[cl], start = offs[cl];
    float a0 = 0.0f, a1 = 0.0f;
    int per = (cnt + 7) >> 3;
    int lo = w * per, hi = min(cnt, lo + per);
    centers_gather((const uint32_t*)xb, ridx, start, lo, hi, l, a0, a1);
    sP[w][l] = make_float2(a0, a1);
    __syncthreads();
    if (w == 0) {
        float c0 = 0.0f, c1 = 0.0f;
#pragma unroll
        for (int q = 0; q < 8; ++q) { c0 += sP[q][l].x; c1 += sP[q][l].y; }
        float fc = fmaxf((float)cnt, 1.0f);
        c0 /= fc; c1 /= fc;
        float ss = c0 * c0 + c1 * c1;
        for (int off = 1; off < 64; off <<= 1) ss += __shfl_xor(ss, off);
        float inv = EXP2_SCALE / fmaxf(sqrtf(ss), 1e-12f);
        ushort2 o;
        o.x = f2bf(c0 * inv); o.y = f2bf(c1 * inv);
        *reinterpret_cast<ushort2*>(cen + (size_t)cl * DDIM + l * 2) = o;
        if (l == 0)
            atomicAdd(out, -(float)cnt * sqrtf(ss) * (INV_BETA / (float)NROWS));
    }
}

// K4 v10: exact v8 structure (fragment-ordered LDS, single acc — MfmaUtil 52 +
// VALUBusy 48 = issue-saturated; both ping-pong variants regressed) with one
// non-scheduling change: den[8] (split by rr parity) halves the serial
// dependent-add chain on exp2 results.
__global__ __launch_bounds__(1024) void k4_loss(
    const unsigned short* __restrict__ xb, const unsigned short* __restrict__ cen,
    const float* __restrict__ nabsG, float* __restrict__ out) {
    extern __shared__ char lds[];
    char* cenL = lds;                       // 131072
    float* wsum = (float*)(lds + 131072);   // 16 f32
    int t = threadIdx.x, w = t >> 6, l = t & 63;
    int lm = l & 15, lk = l >> 4;
    float nabs = *nabsG;

    int s0 = blockIdx.x * 1024 + w * 64;
    const char* xB = (const char*)xb;
    v8bf bfr[4][4];
#pragma unroll
    for (int n = 0; n < 4; ++n)
#pragma unroll
        for (int kc = 0; kc < 4; ++kc)
            bfr[n][kc] = *reinterpret_cast<const v8bf*>(
                xB + (size_t)(s0 + n * 16 + lm) * 256 + kc * 64 + lk * 16);

    const char* cB = (const char*)cen;
#pragma unroll
    for (int i = 0; i < 8; ++i) {
        int chunk = w * 8 + i;            // 0..127
        int m = chunk >> 2, kc = chunk & 3;
        int src = (m * 16 + lm) * 256 + kc * 64 + lk * 16;
        GLL16(cB + src, cenL + chunk * 1024);
    }
    asm volatile("s_waitcnt vmcnt(0)" ::: "memory");
    __syncthreads();

    float den[8] = {0.0f, 0.0f, 0.0f, 0.0f, 0.0f, 0.0f, 0.0f, 0.0f};
    for (int m = 0; m < 32; ++m) {
        v8bf a[4];
#pragma unroll
        for (int kc = 0; kc < 4; ++kc)
            a[kc] = *reinterpret_cast<const v8bf*>(cenL + m * 4096 + kc * 1024 + l * 16);
        v4f acc[4];
        v4f zero = {0.0f, 0.0f, 0.0f, 0.0f};
#pragma unroll
        for (int n = 0; n < 4; ++n) acc[n] = zero;
#pragma unroll
        for (int kc = 0; kc < 4; ++kc)
#pragma unroll
            for (int n = 0; n < 4; ++n)
                acc[n] = __builtin_amdgcn_mfma_f32_16x16x32_bf16(a[kc], bfr[n][kc], acc[n], 0, 0, 0);
#pragma unroll
        for (int n = 0; n < 4; ++n)
#pragma unroll
            for (int rr = 0; rr < 4; ++rr)
                den[n + ((rr & 1) << 2)] += __builtin_amdgcn_exp2f(acc[n][rr]);
    }

    float lossAcc = 0.0f;
#pragma unroll
    for (int n = 0; n < 4; ++n) {
        float d = den[n] + den[n + 4];
        d += __shfl_xor(d, 16);
        d += __shfl_xor(d, 32);
        if (l < 16) lossAcc += __logf(d - nabs);
    }
#pragma unroll
    for (int off = 1; off < 64; off <<= 1) lossAcc += __shfl_xor(lossAcc, off);
    if (l == 0) wsum[w] = lossAcc;
    __syncthreads();
    if (t == 0) {
        float s = 0.0f;
#pragma unroll
        for (int q = 0; q < 16; ++q) s += wsum[q];
        atomicAdd(out, s * (1.0f / NROWS));
    }
}

extern "C" void kernel_launch(void* const* d_in, const int* in_sizes, int n_in,
                              void* d_out, int out_size, void* d_ws, size_t ws_size,
                              hipStream_t stream) {
    const float* in = (const float*)d_in[0];
    const int* tgt = (const int*)d_in[1];
    float* out = (float*)d_out;
    char* ws = (char*)d_ws;
    unsigned short* xb = (unsigned short*)(ws);              // 67108864 B
    int* counts = (int*)(ws + 67108864);                     // 2048 B
    int* offs = (int*)(ws + 67110912);                       // 2048 B
    float* nabsG = (float*)(ws + 67112960);                  // 256 B (pad)
    unsigned short* cen = (unsigned short*)(ws + 67115264);  // 131072 B
    int* ridx = (int*)(ws + 67246336);                       // 1048576 B
    int* bh = (int*)(ws + 68294912);                         // 131072 B
    int* base = (int*)(ws + 68557056);                       // 131072 B (unused)

    (void)base;
    (void)hipFuncSetAttribute((const void*)k4_loss,
                              hipFuncAttributeMaxDynamicSharedMemorySize, 131136);

    hipLaunchKernelGGL(k1_normalize, dim3(8192 + NHB), dim3(256), 0, stream, in, tgt, xb, bh);
    hipLaunchKernelGGL(k_scatter, dim3(NHB), dim3(512), 0, stream, bh, tgt, counts, offs, ridx, nabsG, out);
    hipLaunchKernelGGL(k_centers, dim3(NCLS), dim3(512), 0, stream, xb, ridx, counts, offs, cen, out);
    hipLaunchKernelGGL(k4_loss, dim3(256), dim3(1024), 131136, stream, xb, cen, nabsG, out);
}

// Round 25
// 108.229 us; speedup vs baseline: 3.0367x; 1.0730x over previous
//
#include <hip/hip_runtime.h>
#include <stdint.h>

#define NROWS 262144
#define DDIM 128
#define NCLS 512
#define NHB 64  // hist/scatter blocks
constexpr float INV_BETA = 10.0f;
constexpr float EXP2_SCALE = 14.426950408889634f;  // 10 * log2(e)

typedef __bf16 v8bf __attribute__((ext_vector_type(8)));
typedef float v4f __attribute__((ext_vector_type(4)));

__device__ inline unsigned short f2bf(float f) {
    uint32_t u = __builtin_bit_cast(uint32_t, f);
    u += 0x7FFFu + ((u >> 16) & 1u);
    return (unsigned short)(u >> 16);
}
__device__ inline float bflo(uint32_t u) { return __builtin_bit_cast(float, u << 16); }
__device__ inline float bfhi(uint32_t u) { return __builtin_bit_cast(float, u & 0xFFFF0000u); }

#define GLL16(gsrc, ldst)                                                        \
    __builtin_amdgcn_global_load_lds(                                            \
        (const __attribute__((address_space(1))) void*)(uintptr_t)(gsrc),        \
        (__attribute__((address_space(3))) void*)(uintptr_t)(ldst), 16, 0, 0)

// K1 v5: streaming L2-normalize fp32 -> bf16 (blocks 0..8191); histogram fused.
__global__ __launch_bounds__(256) void k1_normalize(
    const float* __restrict__ in, const int* __restrict__ tgt,
    unsigned short* __restrict__ xb, int* __restrict__ bh) {
    __shared__ int h[NCLS];
    int t = threadIdx.x;
    if (blockIdx.x >= 8192) {
        int b = blockIdx.x - 8192;
        for (int i = t; i < NCLS; i += 256) h[i] = 0;
        __syncthreads();
        int base = b * (NROWS / NHB);
        for (int i = base + t; i < base + NROWS / NHB; i += 256)
            atomicAdd(&h[tgt[i]], 1);
        __syncthreads();
        for (int i = t; i < NCLS; i += 256)
            bh[b * NCLS + i] = h[i];
        return;
    }
    int w = t >> 6;
    int half = (t & 63) >> 5;
    int lane32 = t & 31;
    int hw = blockIdx.x * 8 + w * 2 + half;
    int r0 = hw * 4;
    float4 v[4];
#pragma unroll
    for (int j = 0; j < 4; ++j)
        v[j] = *reinterpret_cast<const float4*>(in + (size_t)(r0 + j) * DDIM + lane32 * 4);
    float s[4];
#pragma unroll
    for (int j = 0; j < 4; ++j)
        s[j] = v[j].x * v[j].x + v[j].y * v[j].y + v[j].z * v[j].z + v[j].w * v[j].w;
#pragma unroll
    for (int off = 1; off < 32; off <<= 1) {
#pragma unroll
        for (int j = 0; j < 4; ++j) s[j] += __shfl_xor(s[j], off);
    }
#pragma unroll
    for (int j = 0; j < 4; ++j) {
        float iv = rsqrtf(fmaxf(s[j], 1e-24f));
        ushort4 o;
        o.x = f2bf(v[j].x * iv); o.y = f2bf(v[j].y * iv);
        o.z = f2bf(v[j].z * iv); o.w = f2bf(v[j].w * iv);
        *reinterpret_cast<ushort4*>(xb + (size_t)(r0 + j) * DDIM + lane32 * 4) = o;
    }
}

// Prefix v3: bh column register-resident; no serial load-latency chain.
__global__ __launch_bounds__(512) void k_prefix(
    const int* __restrict__ bh, int* __restrict__ counts, int* __restrict__ offs,
    int* __restrict__ base, float* __restrict__ nabsG, float* __restrict__ out) {
    __shared__ int sc[NCLS];
    __shared__ int za;
    int t = threadIdx.x;
    int arr[NHB];
#pragma unroll
    for (int b = 0; b < NHB; ++b) arr[b] = bh[b * NCLS + t];
    int cnt = 0;
#pragma unroll
    for (int b = 0; b < NHB; ++b) cnt += arr[b];
    counts[t] = cnt;
    sc[t] = cnt;
    if (t == 0) za = 0;
    __syncthreads();
    for (int off = 1; off < NCLS; off <<= 1) {
        int v = (t >= off) ? sc[t - off] : 0;
        __syncthreads();
        sc[t] += v;
        __syncthreads();
    }
    int excl = sc[t] - cnt;
    offs[t] = excl;
    if (cnt == 0) atomicAdd(&za, 1);
    int run = excl;
#pragma unroll
    for (int b = 0; b < NHB; ++b) {
        base[b * NCLS + t] = run;
        run += arr[b];
    }
    __syncthreads();
    if (t == 0) { *nabsG = (float)za; *out = 0.0f; }
}

__global__ __launch_bounds__(256) void k_scatter(
    const int* __restrict__ tgt, const int* __restrict__ base, int* __restrict__ ridx) {
    __shared__ int cur[NCLS];
    int t = threadIdx.x;
    int b = blockIdx.x;
    cur[t] = base[b * NCLS + t];
    cur[t + 256] = base[b * NCLS + t + 256];
    __syncthreads();
    int r0 = b * (NROWS / NHB);
    for (int i = t; i < NROWS / NHB; i += 256) {
        int row = r0 + i;
        int c = tgt[row];
        int pos = atomicAdd(&cur[c], 1);
        ridx[pos] = row;
    }
}

// centers gather body (MLP 16).
__device__ inline void centers_gather(
    const uint32_t* __restrict__ xb32, const int* __restrict__ ridx,
    int start, int lo, int hi, int l, float& a0, float& a1) {
    int i = lo;
    for (; i + 16 <= hi; i += 16) {
        int id[16]; uint32_t v[16];
#pragma unroll
        for (int j = 0; j < 16; ++j) id[j] = ridx[start + i + j];
#pragma unroll
        for (int j = 0; j < 16; ++j) v[j] = xb32[(size_t)id[j] * 64 + l];
#pragma unroll
        for (int j = 0; j < 16; ++j) { a0 += bflo(v[j]); a1 += bfhi(v[j]); }
    }
    for (; i < hi; ++i) {
        uint32_t v = xb32[(size_t)ridx[start + i] * 64 + l];
        a0 += bflo(v); a1 += bfhi(v);
    }
}

// Per-class mean + L2-normalize -> bf16 centers pre-scaled by 10*log2(e).
__global__ __launch_bounds__(512) void k_centers(
    const unsigned short* __restrict__ xb, const int* __restrict__ ridx,
    const int* __restrict__ counts, const int* __restrict__ offs,
    unsigned short* __restrict__ cen, float* __restrict__ out) {
    __shared__ float2 sP[8][64];
    int t = threadIdx.x, w = t >> 6, l = t & 63;
    int cl = blockIdx.x;
    int cnt = counts[cl], start = offs[cl];
    float a0 = 0.0f, a1 = 0.0f;
    int per = (cnt + 7) >> 3;
    int lo = w * per, hi = min(cnt, lo + per);
    centers_gather((const uint32_t*)xb, ridx, start, lo, hi, l, a0, a1);
    sP[w][l] = make_float2(a0, a1);
    __syncthreads();
    if (w == 0) {
        float c0 = 0.0f, c1 = 0.0f;
#pragma unroll
        for (int q = 0; q < 8; ++q) { c0 += sP[q][l].x; c1 += sP[q][l].y; }
        float fc = fmaxf((float)cnt, 1.0f);
        c0 /= fc; c1 /= fc;
        float ss = c0 * c0 + c1 * c1;
        for (int off = 1; off < 64; off <<= 1) ss += __shfl_xor(ss, off);
        float inv = EXP2_SCALE / fmaxf(sqrtf(ss), 1e-12f);
        ushort2 o;
        o.x = f2bf(c0 * inv); o.y = f2bf(c1 * inv);
        *reinterpret_cast<ushort2*>(cen + (size_t)cl * DDIM + l * 2) = o;
        if (l == 0)
            atomicAdd(out, -(float)cnt * sqrtf(ss) * (INV_BETA / (float)NROWS));
    }
}

// K4 v8 (best measured): fragment-ordered LDS (conflict-free stride-1
// ds_read_b128), reg-resident B-frags, barrier-free m-sweep, single acc.
// Main loop is MFMA-throughput-bound: MfmaUtil 52% = ~94% of the per-CU
// matrix-pipe ceiling (2.1e6 MFMAs / 256 CU x 4.85 cyc = 16.6 us floor).
__global__ __launch_bounds__(1024) void k4_loss(
    const unsigned short* __restrict__ xb, const unsigned short* __restrict__ cen,
    const float* __restrict__ nabsG, float* __restrict__ out) {
    extern __shared__ char lds[];
    char* cenL = lds;                       // 131072
    float* wsum = (float*)(lds + 131072);   // 16 f32
    int t = threadIdx.x, w = t >> 6, l = t & 63;
    int lm = l & 15, lk = l >> 4;
    float nabs = *nabsG;

    int s0 = blockIdx.x * 1024 + w * 64;
    const char* xB = (const char*)xb;
    v8bf bfr[4][4];
#pragma unroll
    for (int n = 0; n < 4; ++n)
#pragma unroll
        for (int kc = 0; kc < 4; ++kc)
            bfr[n][kc] = *reinterpret_cast<const v8bf*>(
                xB + (size_t)(s0 + n * 16 + lm) * 256 + kc * 64 + lk * 16);

    const char* cB = (const char*)cen;
#pragma unroll
    for (int i = 0; i < 8; ++i) {
        int chunk = w * 8 + i;            // 0..127
        int m = chunk >> 2, kc = chunk & 3;
        int src = (m * 16 + lm) * 256 + kc * 64 + lk * 16;
        GLL16(cB + src, cenL + chunk * 1024);
    }
    asm volatile("s_waitcnt vmcnt(0)" ::: "memory");
    __syncthreads();

    float den[4] = {0.0f, 0.0f, 0.0f, 0.0f};
    for (int m = 0; m < 32; ++m) {
        v8bf a[4];
#pragma unroll
        for (int kc = 0; kc < 4; ++kc)
            a[kc] = *reinterpret_cast<const v8bf*>(cenL + m * 4096 + kc * 1024 + l * 16);
        v4f acc[4];
        v4f zero = {0.0f, 0.0f, 0.0f, 0.0f};
#pragma unroll
        for (int n = 0; n < 4; ++n) acc[n] = zero;
#pragma unroll
        for (int kc = 0; kc < 4; ++kc)
#pragma unroll
            for (int n = 0; n < 4; ++n)
                acc[n] = __builtin_amdgcn_mfma_f32_16x16x32_bf16(a[kc], bfr[n][kc], acc[n], 0, 0, 0);
#pragma unroll
        for (int n = 0; n < 4; ++n)
#pragma unroll
            for (int rr = 0; rr < 4; ++rr)
                den[n] += __builtin_amdgcn_exp2f(acc[n][rr]);
    }

    float lossAcc = 0.0f;
#pragma unroll
    for (int n = 0; n < 4; ++n) {
        float d = den[n];
        d += __shfl_xor(d, 16);
        d += __shfl_xor(d, 32);
        if (l < 16) lossAcc += __logf(d - nabs);
    }
#pragma unroll
    for (int off = 1; off < 64; off <<= 1) lossAcc += __shfl_xor(lossAcc, off);
    if (l == 0) wsum[w] = lossAcc;
    __syncthreads();
    if (t == 0) {
        float s = 0.0f;
#pragma unroll
        for (int q = 0; q < 16; ++q) s += wsum[q];
        atomicAdd(out, s * (1.0f / NROWS));
    }
}

extern "C" void kernel_launch(void* const* d_in, const int* in_sizes, int n_in,
                              void* d_out, int out_size, void* d_ws, size_t ws_size,
                              hipStream_t stream) {
    const float* in = (const float*)d_in[0];
    const int* tgt = (const int*)d_in[1];
    float* out = (float*)d_out;
    char* ws = (char*)d_ws;
    unsigned short* xb = (unsigned short*)(ws);              // 67108864 B
    int* counts = (int*)(ws + 67108864);                     // 2048 B
    int* offs = (int*)(ws + 67110912);                       // 2048 B
    float* nabsG = (float*)(ws + 67112960);                  // 256 B (pad)
    unsigned short* cen = (unsigned short*)(ws + 67115264);  // 131072 B
    int* ridx = (int*)(ws + 67246336);                       // 1048576 B
    int* bh = (int*)(ws + 68294912);                         // 131072 B
    int* base = (int*)(ws + 68557056);                       // 131072 B

    (void)hipFuncSetAttribute((const void*)k4_loss,
                              hipFuncAttributeMaxDynamicSharedMemorySize, 131136);

    hipLaunchKernelGGL(k1_normalize, dim3(8192 + NHB), dim3(256), 0, stream, in, tgt, xb, bh);
    hipLaunchKernelGGL(k_prefix, dim3(1), dim3(512), 0, stream, bh, counts, offs, base, nabsG, out);
    hipLaunchKernelGGL(k_scatter, dim3(NHB), dim3(256), 0, stream, tgt, base, ridx);
    hipLaunchKernelGGL(k_centers, dim3(NCLS), dim3(512), 0, stream, xb, ridx, counts, offs, cen, out);
    hipLaunchKernelGGL(k4_loss, dim3(256), dim3(1024), 131136, stream, xb, cen, nabsG, out);
}